// Round 3
// baseline (242.972 us; speedup 1.0000x reference)
//
#include <hip/hip_runtime.h>
#include <hip/hip_fp16.h>

// Problem constants
#define NN    256   // NUM_NODES
#define SS    4     // NUM_FSM_STATES
#define TT    3     // NUM_EDGE_TYPES
#define VV    4     // NUM_VARIANTS
#define NTY   8     // NUM_NODE_TYPES
#define NAC   15    // n_actions = T*S + 3
#define CAPG  48    // max packed pair-groups per col (96 edges; deg~Poi(38.4))
#define CAPE  (CAPG * 2)
#define ROWB  40    // bytes per tmp row (12 halves used + pad)
#define ZROWB (NN * ROWB)       // zero pad row byte offset = 10240 (fits u16)
#define BUFB  (ZROWB + ROWB)    // bytes per tmp buffer
#define ZPK   ((unsigned)ZROWB | ((unsigned)ZROWB << 16))
#define GMR4  8     // per-thread quarter-group regs (covers 32 groups = 64 edges)

typedef _Float16 h2v __attribute__((ext_vector_type(2)));

#if defined(__has_builtin)
#if __has_builtin(__builtin_amdgcn_fdot2)
#define HAVE_FDOT2 1
#endif
#endif

static __device__ __forceinline__ unsigned ph2(float a, float b) {
    union { __half2 h; unsigned u; } c;
    c.h = __floats2half2_rn(a, b);
    return c.u;
}
static __device__ __forceinline__ h2v bch2(unsigned u) {
    union { unsigned u; h2v h; } c; c.u = u; return c.h;
}
static __device__ __forceinline__ float2 h2f2(unsigned u) {
    union { unsigned u; __half2 h; } c; c.u = u; return __half22float2(c.h);
}

// ---------------------------------------------------------------------------
// Setup (unchanged from round 2):
//   blocks 0..767      : inv_deg row sums (coalesced, wave+LDS reduce)
//   blocks 768..831    : per-col edge build, 4 cols/block via float4 reads
//   block  832         : routing softmax
__global__ void k_setup(const float* __restrict__ adj,
                        const float* __restrict__ lrp,
                        float* __restrict__ inv_deg,
                        float* __restrict__ pol,
                        unsigned* __restrict__ epk,
                        int* __restrict__ gcnt) {
    const int b = blockIdx.x;
    const int tid = threadIdx.x;

    if (b < TT * NN) {
        __shared__ float wsum[4];
        float s = adj[(size_t)b * NN + tid];
#pragma unroll
        for (int off = 32; off > 0; off >>= 1) s += __shfl_down(s, off, 64);
        if ((tid & 63) == 0) wsum[tid >> 6] = s;
        __syncthreads();
        if (tid == 0)
            inv_deg[b] = 1.0f / fmaxf(wsum[0] + wsum[1] + wsum[2] + wsum[3], 1.0f);
    } else if (b < TT * NN + 64) {
        // edge lists for 4 columns: thread row=tid tests (t,tid,c4..c4+3)
        __shared__ int cnt[4];
        __shared__ unsigned short offs[4][CAPE + 2];
        const int c4 = (b - TT * NN) * 4;
        if (tid < 4) cnt[tid] = 0;
        __syncthreads();
#pragma unroll
        for (int t = 0; t < TT; t++) {
            const float4 a4 = *(const float4*)(adj + ((size_t)t * NN + tid) * NN + c4);
            const float av[4] = {a4.x, a4.y, a4.z, a4.w};
#pragma unroll
            for (int c = 0; c < 4; c++) {
                if (av[c] != 0.f) {
                    int idx = atomicAdd(&cnt[c], 1);
                    if (idx < CAPE) offs[c][idx] = (unsigned short)(tid * ROWB + t * 8);
                }
            }
        }
        __syncthreads();
        const int c    = tid >> 6;       // one wave per column
        const int lane = tid & 63;
        int cc = cnt[c]; if (cc > CAPE) cc = CAPE;
        if (lane == 0 && (cc & 1)) offs[c][cc] = (unsigned short)ZROWB;  // pad odd
        __syncthreads();
        const int g = (cc + 1) >> 1;
        for (int gg = lane; gg < g; gg += 64)
            epk[(size_t)gg * NN + (c4 + c)] =
                (unsigned)offs[c][2 * gg] | ((unsigned)offs[c][2 * gg + 1] << 16);
        if (lane == 0) gcnt[c4 + c] = g;
    } else {
        if (tid < VV * NTY * SS) {
            float x[NAC]; float m = -3.4e38f;
#pragma unroll
            for (int a = 0; a < NAC; a++) { x[a] = lrp[tid * NAC + a]; m = fmaxf(m, x[a]); }
            float ssum = 0.f;
#pragma unroll
            for (int a = 0; a < NAC; a++) { x[a] = __expf(x[a] - m); ssum += x[a]; }
            float inv = 1.f / ssum;
#pragma unroll
            for (int a = 0; a < NAC; a++) pol[tid * NAC + a] = x[a] * inv;
        }
    }
}

// ---------------------------------------------------------------------------
// Main loop: grid 512 = (e,i); block 1024 threads = 4 threads per col.
//   col = tid>>2, h = tid&3.
//   Phase A: h=0,1,2 own t-slice t=h of the tmp row (4 actions, one 8B
//   ds_write_b64); h=3 owns accept+back.
//   Phase B: thread h gathers groups k with k%4==h; 2-step shfl_xor
//   butterfly over the 4 adjacent lanes combines the partial sums.
//
//   __launch_bounds__(1024, 2): round-2's (1024,8) second arg behaved as
//   CUDA min-BLOCKS/CU (8 blocks impossible -> VGPR crushed to 32 + scratch
//   spills, FETCH 12MB/WRITE 25MB).  (1024,2) = 2 blocks * 16 waves =
//   32 waves/CU -> VGPR cap 64, which the trimmed body genuinely fits:
//   pm 16 + ep 8 + acc 4 (single set) + D 4 + tv 4 + temps ~ 55.
__global__ __launch_bounds__(1024, 2) void k_main(
    const float* __restrict__ vw,
    const int* __restrict__ node_types,
    const float* __restrict__ pol,
    const float* __restrict__ inv_deg,
    const unsigned* __restrict__ epk,
    const int* __restrict__ gcnt,
    const int* __restrict__ steps_p,
    float* __restrict__ out)
{
    const int i    = blockIdx.x & 255;
    const int e    = blockIdx.x >> 8;
    const int tid  = threadIdx.x;
    const int col  = tid >> 2;
    const int h    = tid & 3;
    const int lane = tid & 63;
    const int wv   = tid >> 6;          // 16 waves
    const int steps = steps_p[0];

    __shared__ __align__(16) char tmpb[2 * BUFB];   // 20.6 KB
    __shared__ __align__(16) float backp[2][16];

    if (tid < 20) {
        int pb = tid / 10, w = tid % 10;
        ((unsigned*)(tmpb + pb * BUFB + ZROWB))[w] = 0u;
    }

    // --- per-(col,h) mixed policy slice ---
    //   h<3 : pm[s][u] = mixed p_move for action t=h, dest u  (scaled 1/deg)
    //   h==3: pm[s][0] = p_accept, pm[s][1] = p_back (pm[s][2..3] unused)
    const float4 w4 = *(const float4*)(vw + ((size_t)i * NN + col) * VV);
    const float wvv[VV] = {w4.x, w4.y, w4.z, w4.w};
    const int ntj = node_types[col];
    int ai[4];
    if (h < 3) { ai[0] = 4 * h; ai[1] = 4 * h + 1; ai[2] = 4 * h + 2; ai[3] = 4 * h + 3; }
    else       { ai[0] = 12;    ai[1] = 13;        ai[2] = 14;        ai[3] = 14;        }
    float pm[SS][4];
#pragma unroll
    for (int s = 0; s < SS; s++)
#pragma unroll
        for (int u = 0; u < 4; u++) pm[s][u] = 0.f;
#pragma unroll
    for (int v = 0; v < VV; v++) {
        const float* pr = pol + (size_t)(v * NTY + ntj) * SS * NAC;
#pragma unroll
        for (int s = 0; s < SS; s++) {
            const float* p = pr + s * NAC;
#pragma unroll
            for (int u = 0; u < 4; u++) pm[s][u] = fmaf(wvv[v], p[ai[u]], pm[s][u]);
        }
    }
    {
        float invd = 1.f;
        if (h < 3) invd = inv_deg[h * NN + col];
#pragma unroll
        for (int s = 0; s < SS; s++)
#pragma unroll
            for (int u = 0; u < 4; u++) pm[s][u] *= invd;
    }

    float D0 = (0 == e && col == i) ? 1.f : 0.f;
    float D1 = (1 == e && col == i) ? 1.f : 0.f;
    float D2 = 0.f, D3 = 0.f;
    float acc = 0.f;

    // --- my quarter of the edge-group list (k%4 == h) into registers ---
    const int g_all = gcnt[col];
    const int ch = (g_all - h + 3) >> 2;     // my group count
    int km = ch;
#pragma unroll
    for (int off = 32; off > 0; off >>= 1) {
        int o = __shfl_xor(km, off, 64);
        km = o > km ? o : km;
    }
    const int kmax = __builtin_amdgcn_readfirstlane(km);   // wave-uniform

    unsigned ep[GMR4];
#pragma unroll
    for (int k = 0; k < GMR4; k++) {
        unsigned pk = epk[(size_t)(4 * k + h) * NN + col];  // in-bounds; junk past g_all
        ep[k] = (4 * k + h < g_all) ? pk : ZPK;             // junk reads zero row
    }

    const h2v S10 = {(_Float16)1.0f, (_Float16)0.0f};
    const h2v S01 = {(_Float16)0.0f, (_Float16)1.0f};
    char* const myrow0 = tmpb + col * ROWB + h * 8;

    for (int step = 0; step < steps; step++) {
        const int par = step & 1;
        char* const buf = tmpb + par * BUFB;

        // ---- phase A (uniform): tv[u] = sum_s D[s]*pm[s][u] ----
        float tv0 = D0 * pm[0][0];
        tv0 = fmaf(D1, pm[1][0], tv0); tv0 = fmaf(D2, pm[2][0], tv0); tv0 = fmaf(D3, pm[3][0], tv0);
        float tv1 = D0 * pm[0][1];
        tv1 = fmaf(D1, pm[1][1], tv1); tv1 = fmaf(D2, pm[2][1], tv1); tv1 = fmaf(D3, pm[3][1], tv1);
        float tv2 = D0 * pm[0][2];
        tv2 = fmaf(D1, pm[1][2], tv2); tv2 = fmaf(D2, pm[2][2], tv2); tv2 = fmaf(D3, pm[3][2], tv2);
        float tv3 = D0 * pm[0][3];
        tv3 = fmaf(D1, pm[1][3], tv3); tv3 = fmaf(D2, pm[2][3], tv3); tv3 = fmaf(D3, pm[3][3], tv3);

        float bj = 0.f;
        if (h == 3) { acc += tv0; bj = tv1; }    // accept & back mass
        else {
            uint2 w; w.x = ph2(tv0, tv1); w.y = ph2(tv2, tv3);
            *(uint2*)(myrow0 + par * BUFB) = w;  // my 8B t-slice
        }

#pragma unroll
        for (int off = 32; off > 0; off >>= 1) bj += __shfl_down(bj, off, 64);
        if (lane == 0) backp[par][wv] = bj;

        __syncthreads();   // the ONLY barrier per step

        // ---- phase B: register-driven gather over my quarter's groups ----
        float d0 = 0.f, d1 = 0.f, d2 = 0.f, d3 = 0.f;
#pragma unroll
        for (int k = 0; k < GMR4; k++) {
            if (k < kmax) {   // kmax in SGPR -> scalar branch
                const unsigned pk = ep[k];
                const uint2 q0 = *(const uint2*)(buf + (pk & 0xffffu));
                const uint2 q1 = *(const uint2*)(buf + (pk >> 16));
#ifdef HAVE_FDOT2
                d0 = __builtin_amdgcn_fdot2(bch2(q0.x), S10, d0, false);
                d1 = __builtin_amdgcn_fdot2(bch2(q0.x), S01, d1, false);
                d2 = __builtin_amdgcn_fdot2(bch2(q0.y), S10, d2, false);
                d3 = __builtin_amdgcn_fdot2(bch2(q0.y), S01, d3, false);
                d0 = __builtin_amdgcn_fdot2(bch2(q1.x), S10, d0, false);
                d1 = __builtin_amdgcn_fdot2(bch2(q1.x), S01, d1, false);
                d2 = __builtin_amdgcn_fdot2(bch2(q1.y), S10, d2, false);
                d3 = __builtin_amdgcn_fdot2(bch2(q1.y), S01, d3, false);
#else
                float2 f0 = h2f2(q0.x), f1 = h2f2(q0.y), f2 = h2f2(q1.x), f3 = h2f2(q1.y);
                d0 += f0.x + f2.x; d1 += f0.y + f2.y;
                d2 += f1.x + f3.x; d3 += f1.y + f3.y;
#endif
            }
        }
        // rare tail beyond register capacity (per-lane guard vs junk entries)
        for (int k = GMR4; k < kmax; k++) {
            unsigned pk = epk[(size_t)(4 * k + h) * NN + col];
            pk = (4 * k + h < g_all) ? pk : ZPK;
            const uint2 q0 = *(const uint2*)(buf + (pk & 0xffffu));
            const uint2 q1 = *(const uint2*)(buf + (pk >> 16));
            float2 f0 = h2f2(q0.x), f1 = h2f2(q0.y), f2 = h2f2(q1.x), f3 = h2f2(q1.y);
            d0 += f0.x + f2.x; d1 += f0.y + f2.y;
            d2 += f1.x + f3.x; d3 += f1.y + f3.y;
        }

        // ---- combine the 4 quarters of each col (adjacent lanes, same wave) ----
        d0 += __shfl_xor(d0, 1, 64);  d0 += __shfl_xor(d0, 2, 64);
        d1 += __shfl_xor(d1, 1, 64);  d1 += __shfl_xor(d1, 2, 64);
        d2 += __shfl_xor(d2, 1, 64);  d2 += __shfl_xor(d2, 2, 64);
        d3 += __shfl_xor(d3, 1, 64);  d3 += __shfl_xor(d3, 2, 64);

        // ---- restart (only the 4 col==i threads need `back`) ----
        if (col == i) {
            const float4 b0 = *(const float4*)(&backp[par][0]);
            const float4 b1 = *(const float4*)(&backp[par][4]);
            const float4 b2 = *(const float4*)(&backp[par][8]);
            const float4 b3 = *(const float4*)(&backp[par][12]);
            const float back = (((b0.x + b0.y) + (b0.z + b0.w)) +
                                ((b1.x + b1.y) + (b1.z + b1.w))) +
                               (((b2.x + b2.y) + (b2.z + b2.w)) +
                                ((b3.x + b3.y) + (b3.z + b3.w)));
            if (e == 0) d0 = fmaf(back, 0.999f, d0);
            else        d1 = fmaf(back, 0.999f, d1);
        }
        D0 = d0; D1 = d1; D2 = d2; D3 = d3;
    }

    // final accept (h==3 holds p_accept in pm[:,0] and owns the output)
    if (h == 3) {
        float r = D0 * pm[0][0];
        r = fmaf(D1, pm[1][0], r); r = fmaf(D2, pm[2][0], r); r = fmaf(D3, pm[3][0], r);
        acc += r;
        out[((size_t)e * NN + i) * NN + col] = acc;
    }
}

// ---------------------------------------------------------------------------
extern "C" void kernel_launch(void* const* d_in, const int* in_sizes, int n_in,
                              void* d_out, int out_size, void* d_ws, size_t ws_size,
                              hipStream_t stream) {
    const float* vw  = (const float*)d_in[0];   // (N,N,V) fp32
    const float* adj = (const float*)d_in[1];   // (T,N,N) fp32 {0,1}
    const float* lrp = (const float*)d_in[2];   // (V,NTY,S,NAC) fp32
    const int* node_types = (const int*)d_in[3];
    const int* steps_p    = (const int*)d_in[4];

    float* ws       = (float*)d_ws;
    float* pol      = ws;                        // 1920 f
    float* inv_deg  = ws + 1920;                 // 768 f
    int*   gcnt     = (int*)(ws + 2688);         // 256 i
    unsigned* epk   = (unsigned*)(ws + 2944);    // CAPG*NN u32 = 48 KB

    k_setup<<<TT * NN + 64 + 1, 256, 0, stream>>>(adj, lrp, inv_deg, pol, epk, gcnt);
    k_main<<<2 * NN, 1024, 0, stream>>>(vw, node_types, pol, inv_deg, epk, gcnt,
                                        steps_p, (float*)d_out);
}

// Round 4
// 200.524 us; speedup vs baseline: 1.2117x; 1.2117x over previous
//
#include <hip/hip_runtime.h>
#include <hip/hip_fp16.h>

// Problem constants
#define NN    256   // NUM_NODES
#define SS    4     // NUM_FSM_STATES
#define TT    3     // NUM_EDGE_TYPES
#define VV    4     // NUM_VARIANTS
#define NTY   8     // NUM_NODE_TYPES
#define NAC   15    // n_actions = T*S + 3
#define CAPG  48    // max packed pair-groups per col (96 edges; deg~Poi(38.4))
#define CAPE  (CAPG * 2)
// ROWB 36 (was 40): dword stride 9, gcd(9,32)=1 -> row starts spread over all
// 32 LDS banks (stride 10 hit only the 16 even banks -> ~2x conflicts).
// Odd-dword stride means 8B loads can be misaligned, so all tmp accesses are
// paired u32 (ds_read2_b32 / ds_write2_b32), same wave-cycle floor as b64.
#define ROWB  36    // bytes per tmp row (24 used: 12 halves, action-major)
#define ZROWB (NN * ROWB)       // zero pad row byte offset = 9216 (fits u16)
#define BUFB  (ZROWB + ROWB)    // bytes per tmp buffer = 9252
#define ZPK   ((unsigned)ZROWB | ((unsigned)ZROWB << 16))
#define GMR   16    // per-thread (per-parity-half) group regs; covers wave-max ~14

typedef _Float16 h2v __attribute__((ext_vector_type(2)));

#if defined(__has_builtin)
#if __has_builtin(__builtin_amdgcn_fdot2)
#define HAVE_FDOT2 1
#endif
#endif

static __device__ __forceinline__ unsigned ph2(float a, float b) {
    union { __half2 h; unsigned u; } c;
    c.h = __floats2half2_rn(a, b);
    return c.u;
}
static __device__ __forceinline__ h2v bch2(unsigned u) {
    union { unsigned u; h2v h; } c; c.u = u; return c.h;
}
static __device__ __forceinline__ float2 h2f2(unsigned u) {
    union { unsigned u; __half2 h; } c; c.u = u; return __half22float2(c.h);
}

// ---------------------------------------------------------------------------
// Setup:
//   blocks 0..767      : inv_deg row sums (coalesced, wave+LDS reduce)
//   blocks 768..831    : per-col edge build, 4 cols/block via float4 reads
//   block  832         : routing softmax
__global__ void k_setup(const float* __restrict__ adj,
                        const float* __restrict__ lrp,
                        float* __restrict__ inv_deg,
                        float* __restrict__ pol,
                        unsigned* __restrict__ epk,
                        int* __restrict__ gcnt) {
    const int b = blockIdx.x;
    const int tid = threadIdx.x;

    if (b < TT * NN) {
        __shared__ float wsum[4];
        float s = adj[(size_t)b * NN + tid];
#pragma unroll
        for (int off = 32; off > 0; off >>= 1) s += __shfl_down(s, off, 64);
        if ((tid & 63) == 0) wsum[tid >> 6] = s;
        __syncthreads();
        if (tid == 0)
            inv_deg[b] = 1.0f / fmaxf(wsum[0] + wsum[1] + wsum[2] + wsum[3], 1.0f);
    } else if (b < TT * NN + 64) {
        // edge lists for 4 columns: thread row=tid tests (t,tid,c4..c4+3)
        __shared__ int cnt[4];
        __shared__ unsigned short offs[4][CAPE + 2];
        const int c4 = (b - TT * NN) * 4;
        if (tid < 4) cnt[tid] = 0;
        __syncthreads();
#pragma unroll
        for (int t = 0; t < TT; t++) {
            const float4 a4 = *(const float4*)(adj + ((size_t)t * NN + tid) * NN + c4);
            const float av[4] = {a4.x, a4.y, a4.z, a4.w};
#pragma unroll
            for (int c = 0; c < 4; c++) {
                if (av[c] != 0.f) {
                    int idx = atomicAdd(&cnt[c], 1);
                    if (idx < CAPE) offs[c][idx] = (unsigned short)(tid * ROWB + t * 8);
                }
            }
        }
        __syncthreads();
        const int c    = tid >> 6;       // one wave per column
        const int lane = tid & 63;
        int cc = cnt[c]; if (cc > CAPE) cc = CAPE;
        if (lane == 0 && (cc & 1)) offs[c][cc] = (unsigned short)ZROWB;  // pad odd
        __syncthreads();
        const int g = (cc + 1) >> 1;
        for (int gg = lane; gg < g; gg += 64)
            epk[(size_t)gg * NN + (c4 + c)] =
                (unsigned)offs[c][2 * gg] | ((unsigned)offs[c][2 * gg + 1] << 16);
        if (lane == 0) gcnt[c4 + c] = g;
    } else {
        if (tid < VV * NTY * SS) {
            float x[NAC]; float m = -3.4e38f;
#pragma unroll
            for (int a = 0; a < NAC; a++) { x[a] = lrp[tid * NAC + a]; m = fmaxf(m, x[a]); }
            float ssum = 0.f;
#pragma unroll
            for (int a = 0; a < NAC; a++) { x[a] = __expf(x[a] - m); ssum += x[a]; }
            float inv = 1.f / ssum;
#pragma unroll
            for (int a = 0; a < NAC; a++) pol[tid * NAC + a] = x[a] * inv;
        }
    }
}

// ---------------------------------------------------------------------------
// Main loop: grid 512 = (e,i); block 512 threads = 2 threads per col
// (round-1 proven structure: 115us, VGPR 64, 2 blocks/CU = 16 waves/CU;
//  1024-thr blocks empirically never co-reside -> abandoned).
//   col = tid>>1, h = tid&1.  Thread h owns groups g%2==h and action slice
//   [6h, 6h+6).  Partials combined with __shfl_xor(.,1); single barrier/step.
//   This round: ROWB 36 for full-bank spread of the data-dependent gather.
__global__ __launch_bounds__(512, 4) void k_main(
    const float* __restrict__ vw,
    const int* __restrict__ node_types,
    const float* __restrict__ pol,
    const float* __restrict__ inv_deg,
    const unsigned* __restrict__ epk,
    const int* __restrict__ gcnt,
    const int* __restrict__ steps_p,
    float* __restrict__ out)
{
    const int i    = blockIdx.x & 255;
    const int e    = blockIdx.x >> 8;
    const int tid  = threadIdx.x;
    const int col  = tid >> 1;
    const int h    = tid & 1;
    const int lane = tid & 63;
    const int wv   = tid >> 6;          // 8 waves
    const int steps = steps_p[0];

    __shared__ __align__(16) char tmpb[2 * BUFB];   // 18.5 KB
    __shared__ __align__(16) float backp[2][8];

    if (tid < 18) {   // zero pad row: 9 dwords per buffer
        int pb = tid / 9, w = tid % 9;
        ((unsigned*)(tmpb + pb * BUFB + ZROWB))[w] = 0u;
    }

    // --- per-(col,half) mixed policy slice, pre-scaled by inv_deg ---
    const float4 w4 = *(const float4*)(vw + ((size_t)i * NN + col) * VV);
    const float wvv[VV] = {w4.x, w4.y, w4.z, w4.w};
    const int ntj = node_types[col];
    const int ab  = h * 6;              // this half's action base
    float pm6[SS][6], pcb[SS];
#pragma unroll
    for (int s = 0; s < SS; s++) {
        pcb[s] = 0.f;
#pragma unroll
        for (int a = 0; a < 6; a++) pm6[s][a] = 0.f;
    }
#pragma unroll
    for (int v = 0; v < VV; v++) {
        const float* pr = pol + (size_t)(v * NTY + ntj) * SS * NAC;
#pragma unroll
        for (int s = 0; s < SS; s++) {
            const float* p = pr + s * NAC;
#pragma unroll
            for (int a = 0; a < 6; a++) pm6[s][a] = fmaf(wvv[v], p[ab + a], pm6[s][a]);
            pcb[s] = fmaf(wvv[v], p[12 + h], pcb[s]);   // h0: accept, h1: back
        }
    }
    {
        float invd[TT];
#pragma unroll
        for (int t = 0; t < TT; t++) invd[t] = inv_deg[t * NN + col];
#pragma unroll
        for (int s = 0; s < SS; s++)
#pragma unroll
            for (int a = 0; a < 6; a++) pm6[s][a] *= invd[(ab + a) >> 2];
    }

    float D0 = (0 == e && col == i) ? 1.f : 0.f;
    float D1 = (1 == e && col == i) ? 1.f : 0.f;
    float D2 = 0.f, D3 = 0.f;
    float acc = 0.f;

    // --- this half's edge list (groups with parity h) into registers ---
    const int g_all = gcnt[col];
    const int ch = (g_all - h + 1) >> 1;     // my group count
    int km = ch;
#pragma unroll
    for (int off = 32; off > 0; off >>= 1) {
        int o = __shfl_xor(km, off, 64);
        km = o > km ? o : km;
    }
    const int kmax = __builtin_amdgcn_readfirstlane(km);   // wave-uniform

    unsigned ep[GMR];
#pragma unroll
    for (int k = 0; k < GMR; k++) {
        unsigned pk = epk[(size_t)(2 * k + h) * NN + col];  // in-bounds; junk past g_all
        ep[k] = (2 * k + h < g_all) ? pk : ZPK;             // junk reads zero row (bcast)
    }

    const h2v S10 = {(_Float16)1.0f, (_Float16)0.0f};
    const h2v S01 = {(_Float16)0.0f, (_Float16)1.0f};
    char* const myrow0 = tmpb + col * ROWB + h * 12;

    for (int step = 0; step < steps; step++) {
        const int par = step & 1;
        char* const buf = tmpb + par * BUFB;

        // ---- phase A: accept(h0)/back(h1) + my 12B of the fp16 tmp row ----
        float r4 = D0 * pcb[0];
        r4 = fmaf(D1, pcb[1], r4); r4 = fmaf(D2, pcb[2], r4); r4 = fmaf(D3, pcb[3], r4);
        if (h == 0) acc += r4;
        float bj = h ? r4 : 0.f;

        float tv[6];
#pragma unroll
        for (int a = 0; a < 6; a++) {
            float x = D0 * pm6[0][a];
            x = fmaf(D1, pm6[1][a], x);
            x = fmaf(D2, pm6[2][a], x);
            x = fmaf(D3, pm6[3][a], x);
            tv[a] = x;
        }
        char* const myrow = myrow0 + par * BUFB;
        *(unsigned*)(myrow)     = ph2(tv[0], tv[1]);
        *(unsigned*)(myrow + 4) = ph2(tv[2], tv[3]);
        *(unsigned*)(myrow + 8) = ph2(tv[4], tv[5]);

        // back-mass wave reduce: bj lives on odd lanes only -> stride-2 tree
#pragma unroll
        for (int off = 2; off <= 32; off <<= 1) bj += __shfl_down(bj, off, 64);
        if (lane == 1) backp[par][wv] = bj;

        __syncthreads();   // the ONLY barrier per step

        // ---- phase B: register-driven gather, dual accumulator sets ----
        float d0a = 0.f, d1a = 0.f, d2a = 0.f, d3a = 0.f;
        float d0b = 0.f, d1b = 0.f, d2b = 0.f, d3b = 0.f;
#pragma unroll
        for (int k = 0; k < GMR; k++) {
            if (k < kmax) {   // kmax in SGPR -> scalar branch, no VALU
                const unsigned pk = ep[k];
                const char* p0 = buf + (pk & 0xffffu);
                const char* p1 = buf + (pk >> 16);
                const unsigned q0x = *(const unsigned*)(p0);
                const unsigned q0y = *(const unsigned*)(p0 + 4);
                const unsigned q1x = *(const unsigned*)(p1);
                const unsigned q1y = *(const unsigned*)(p1 + 4);
#ifdef HAVE_FDOT2
                if (k & 1) {
                    d0b = __builtin_amdgcn_fdot2(bch2(q0x), S10, d0b, false);
                    d1b = __builtin_amdgcn_fdot2(bch2(q0x), S01, d1b, false);
                    d2b = __builtin_amdgcn_fdot2(bch2(q0y), S10, d2b, false);
                    d3b = __builtin_amdgcn_fdot2(bch2(q0y), S01, d3b, false);
                    d0b = __builtin_amdgcn_fdot2(bch2(q1x), S10, d0b, false);
                    d1b = __builtin_amdgcn_fdot2(bch2(q1x), S01, d1b, false);
                    d2b = __builtin_amdgcn_fdot2(bch2(q1y), S10, d2b, false);
                    d3b = __builtin_amdgcn_fdot2(bch2(q1y), S01, d3b, false);
                } else {
                    d0a = __builtin_amdgcn_fdot2(bch2(q0x), S10, d0a, false);
                    d1a = __builtin_amdgcn_fdot2(bch2(q0x), S01, d1a, false);
                    d2a = __builtin_amdgcn_fdot2(bch2(q0y), S10, d2a, false);
                    d3a = __builtin_amdgcn_fdot2(bch2(q0y), S01, d3a, false);
                    d0a = __builtin_amdgcn_fdot2(bch2(q1x), S10, d0a, false);
                    d1a = __builtin_amdgcn_fdot2(bch2(q1x), S01, d1a, false);
                    d2a = __builtin_amdgcn_fdot2(bch2(q1y), S10, d2a, false);
                    d3a = __builtin_amdgcn_fdot2(bch2(q1y), S01, d3a, false);
                }
#else
                float2 f0 = h2f2(q0x), f1 = h2f2(q0y), f2 = h2f2(q1x), f3 = h2f2(q1y);
                if (k & 1) {
                    d0b += f0.x + f2.x; d1b += f0.y + f2.y;
                    d2b += f1.x + f3.x; d3b += f1.y + f3.y;
                } else {
                    d0a += f0.x + f2.x; d1a += f0.y + f2.y;
                    d2a += f1.x + f3.x; d3a += f1.y + f3.y;
                }
#endif
            }
        }
        // rare tail beyond register capacity (per-lane guard vs junk entries)
        for (int k = GMR; k < kmax; k++) {
            unsigned pk = epk[(size_t)(2 * k + h) * NN + col];
            pk = (2 * k + h < g_all) ? pk : ZPK;
            const char* p0 = buf + (pk & 0xffffu);
            const char* p1 = buf + (pk >> 16);
            float2 f0 = h2f2(*(const unsigned*)(p0));
            float2 f1 = h2f2(*(const unsigned*)(p0 + 4));
            float2 f2 = h2f2(*(const unsigned*)(p1));
            float2 f3 = h2f2(*(const unsigned*)(p1 + 4));
            d0a += f0.x + f2.x; d1a += f0.y + f2.y;
            d2a += f1.x + f3.x; d3a += f1.y + f3.y;
        }

        float d0 = d0a + d0b, d1 = d1a + d1b, d2 = d2a + d2b, d3 = d3a + d3b;

        // ---- combine the two halves of each col (same wave, lanes 2c/2c+1) ----
        d0 += __shfl_xor(d0, 1, 64);
        d1 += __shfl_xor(d1, 1, 64);
        d2 += __shfl_xor(d2, 1, 64);
        d3 += __shfl_xor(d3, 1, 64);

        // ---- restart (only the 2 col==i threads need `back`) ----
        if (col == i) {
            const float4 b0 = *(const float4*)(&backp[par][0]);
            const float4 b1 = *(const float4*)(&backp[par][4]);
            const float back = ((b0.x + b0.y) + (b0.z + b0.w)) +
                               ((b1.x + b1.y) + (b1.z + b1.w));
            if (e == 0) d0 = fmaf(back, 0.999f, d0);
            else        d1 = fmaf(back, 0.999f, d1);
        }
        D0 = d0; D1 = d1; D2 = d2; D3 = d3;
    }

    // final accept (h0 holds pacc and writes the output)
    float r4 = D0 * pcb[0];
    r4 = fmaf(D1, pcb[1], r4); r4 = fmaf(D2, pcb[2], r4); r4 = fmaf(D3, pcb[3], r4);
    if (h == 0) {
        acc += r4;
        out[((size_t)e * NN + i) * NN + col] = acc;
    }
}

// ---------------------------------------------------------------------------
extern "C" void kernel_launch(void* const* d_in, const int* in_sizes, int n_in,
                              void* d_out, int out_size, void* d_ws, size_t ws_size,
                              hipStream_t stream) {
    const float* vw  = (const float*)d_in[0];   // (N,N,V) fp32
    const float* adj = (const float*)d_in[1];   // (T,N,N) fp32 {0,1}
    const float* lrp = (const float*)d_in[2];   // (V,NTY,S,NAC) fp32
    const int* node_types = (const int*)d_in[3];
    const int* steps_p    = (const int*)d_in[4];

    float* ws       = (float*)d_ws;
    float* pol      = ws;                        // 1920 f
    float* inv_deg  = ws + 1920;                 // 768 f
    int*   gcnt     = (int*)(ws + 2688);         // 256 i
    unsigned* epk   = (unsigned*)(ws + 2944);    // CAPG*NN u32 = 48 KB

    k_setup<<<TT * NN + 64 + 1, 256, 0, stream>>>(adj, lrp, inv_deg, pol, epk, gcnt);
    k_main<<<2 * NN, 512, 0, stream>>>(vw, node_types, pol, inv_deg, epk, gcnt,
                                       steps_p, (float*)d_out);
}

// Round 5
// 163.353 us; speedup vs baseline: 1.4874x; 1.2275x over previous
//
#include <hip/hip_runtime.h>
#include <hip/hip_fp16.h>

// Problem constants
#define NN    256   // NUM_NODES
#define SS    4     // NUM_FSM_STATES
#define TT    3     // NUM_EDGE_TYPES
#define VV    4     // NUM_VARIANTS
#define NTY   8     // NUM_NODE_TYPES
#define NAC   15    // n_actions = T*S + 3
#define CAPG  48    // max packed pair-groups per col (96 edges; deg~Poi(38.4))
#define CAPE  (CAPG * 2)
#define ROWB  40    // bytes per tmp row (12 halves used + pad) -- r1-verified
#define ZROWB (NN * ROWB)       // zero pad row byte offset = 10240 (fits u16)
#define BUFB  (ZROWB + ROWB)    // bytes per tmp buffer
#define ZPK   ((unsigned)ZROWB | ((unsigned)ZROWB << 16))
#define GMR   16    // per-thread (per-parity-half) group regs; covers wave-max ~14

typedef _Float16 h2v __attribute__((ext_vector_type(2)));

#if defined(__has_builtin)
#if __has_builtin(__builtin_amdgcn_fdot2)
#define HAVE_FDOT2 1
#endif
#endif

static __device__ __forceinline__ unsigned ph2(float a, float b) {
    union { __half2 h; unsigned u; } c;
    c.h = __floats2half2_rn(a, b);
    return c.u;
}
static __device__ __forceinline__ h2v bch2(unsigned u) {
    union { unsigned u; h2v h; } c; c.u = u; return c.h;
}
static __device__ __forceinline__ float2 h2f2(unsigned u) {
    union { unsigned u; __half2 h; } c; c.u = u; return __half22float2(c.h);
}

// ---------------------------------------------------------------------------
// Setup:
//   blocks 0..767      : inv_deg row sums (coalesced, wave+LDS reduce)
//   blocks 768..831    : per-col edge build, 4 cols/block via float4 reads
//   block  832         : routing softmax
__global__ void k_setup(const float* __restrict__ adj,
                        const float* __restrict__ lrp,
                        float* __restrict__ inv_deg,
                        float* __restrict__ pol,
                        unsigned* __restrict__ epk,
                        int* __restrict__ gcnt) {
    const int b = blockIdx.x;
    const int tid = threadIdx.x;

    if (b < TT * NN) {
        __shared__ float wsum[4];
        float s = adj[(size_t)b * NN + tid];
#pragma unroll
        for (int off = 32; off > 0; off >>= 1) s += __shfl_down(s, off, 64);
        if ((tid & 63) == 0) wsum[tid >> 6] = s;
        __syncthreads();
        if (tid == 0)
            inv_deg[b] = 1.0f / fmaxf(wsum[0] + wsum[1] + wsum[2] + wsum[3], 1.0f);
    } else if (b < TT * NN + 64) {
        // edge lists for 4 columns: thread row=tid tests (t,tid,c4..c4+3)
        __shared__ int cnt[4];
        __shared__ unsigned short offs[4][CAPE + 2];
        const int c4 = (b - TT * NN) * 4;
        if (tid < 4) cnt[tid] = 0;
        __syncthreads();
#pragma unroll
        for (int t = 0; t < TT; t++) {
            const float4 a4 = *(const float4*)(adj + ((size_t)t * NN + tid) * NN + c4);
            const float av[4] = {a4.x, a4.y, a4.z, a4.w};
#pragma unroll
            for (int c = 0; c < 4; c++) {
                if (av[c] != 0.f) {
                    int idx = atomicAdd(&cnt[c], 1);
                    if (idx < CAPE) offs[c][idx] = (unsigned short)(tid * ROWB + t * 8);
                }
            }
        }
        __syncthreads();
        const int c    = tid >> 6;       // one wave per column
        const int lane = tid & 63;
        int cc = cnt[c]; if (cc > CAPE) cc = CAPE;
        if (lane == 0 && (cc & 1)) offs[c][cc] = (unsigned short)ZROWB;  // pad odd
        __syncthreads();
        const int g = (cc + 1) >> 1;
        for (int gg = lane; gg < g; gg += 64)
            epk[(size_t)gg * NN + (c4 + c)] =
                (unsigned)offs[c][2 * gg] | ((unsigned)offs[c][2 * gg + 1] << 16);
        if (lane == 0) gcnt[c4 + c] = g;
    } else {
        if (tid < VV * NTY * SS) {
            float x[NAC]; float m = -3.4e38f;
#pragma unroll
            for (int a = 0; a < NAC; a++) { x[a] = lrp[tid * NAC + a]; m = fmaxf(m, x[a]); }
            float ssum = 0.f;
#pragma unroll
            for (int a = 0; a < NAC; a++) { x[a] = __expf(x[a] - m); ssum += x[a]; }
            float inv = 1.f / ssum;
#pragma unroll
            for (int a = 0; a < NAC; a++) pol[tid * NAC + a] = x[a] * inv;
        }
    }
}

// ---------------------------------------------------------------------------
// Degree sort: counting sort of the 256 cols by group count (ascending).
// perm[rank] = col.  Waves of k_main then hold degree-homogeneous columns,
// so the wave-max gather trip (kmax) ~ local mean instead of global tail.
__global__ void k_sort(const int* __restrict__ gcnt, int* __restrict__ perm) {
    __shared__ int base[64];
    const int tid = threadIdx.x;
    if (tid < 64) base[tid] = 0;
    __syncthreads();
    const int g = gcnt[tid] & 63;
    atomicAdd(&base[g], 1);          // histogram
    __syncthreads();
    if (tid == 0) {
        int s = 0;
#pragma unroll
        for (int b = 0; b < 64; b++) { int c = base[b]; base[b] = s; s += c; }
    }
    __syncthreads();
    const int pos = atomicAdd(&base[g], 1);   // cursor within bin
    perm[pos] = tid;
}

// ---------------------------------------------------------------------------
// Main loop: grid 512 = (e,i); block 512 threads = 2 threads per col.
// Round-1 proven structure (115us): col pair per lane pair, ROWB 40, b64
// gather reads, dual accumulator sets, single barrier/step.
// This round: (a) col = perm[rank] degree-sorted so each wave's kmax ~ its
// local mean (removes ~25% junk gather iterations); (b) phase-B chunked 2
// groups per scalar branch -> 4 b64 loads in flight (was 2).
__global__ __launch_bounds__(512, 4) void k_main(
    const float* __restrict__ vw,
    const int* __restrict__ node_types,
    const float* __restrict__ pol,
    const float* __restrict__ inv_deg,
    const unsigned* __restrict__ epk,
    const int* __restrict__ gcnt,
    const int* __restrict__ perm,
    const int* __restrict__ steps_p,
    float* __restrict__ out)
{
    const int i    = blockIdx.x & 255;
    const int e    = blockIdx.x >> 8;
    const int tid  = threadIdx.x;
    const int col  = perm[tid >> 1];    // degree-sorted column assignment
    const int h    = tid & 1;
    const int lane = tid & 63;
    const int wv   = tid >> 6;          // 8 waves
    const int steps = steps_p[0];

    __shared__ __align__(16) char tmpb[2 * BUFB];   // 20.6 KB
    __shared__ __align__(16) float backp[2][8];

    if (tid < 20) {
        int pb = tid / 10, w = tid % 10;
        ((unsigned*)(tmpb + pb * BUFB + ZROWB))[w] = 0u;
    }

    // --- per-(col,half) mixed policy slice, pre-scaled by inv_deg ---
    const float4 w4 = *(const float4*)(vw + ((size_t)i * NN + col) * VV);
    const float wvv[VV] = {w4.x, w4.y, w4.z, w4.w};
    const int ntj = node_types[col];
    const int ab  = h * 6;              // this half's action base
    float pm6[SS][6], pcb[SS];
#pragma unroll
    for (int s = 0; s < SS; s++) {
        pcb[s] = 0.f;
#pragma unroll
        for (int a = 0; a < 6; a++) pm6[s][a] = 0.f;
    }
#pragma unroll
    for (int v = 0; v < VV; v++) {
        const float* pr = pol + (size_t)(v * NTY + ntj) * SS * NAC;
#pragma unroll
        for (int s = 0; s < SS; s++) {
            const float* p = pr + s * NAC;
#pragma unroll
            for (int a = 0; a < 6; a++) pm6[s][a] = fmaf(wvv[v], p[ab + a], pm6[s][a]);
            pcb[s] = fmaf(wvv[v], p[12 + h], pcb[s]);   // h0: accept, h1: back
        }
    }
    {
        float invd[TT];
#pragma unroll
        for (int t = 0; t < TT; t++) invd[t] = inv_deg[t * NN + col];
#pragma unroll
        for (int s = 0; s < SS; s++)
#pragma unroll
            for (int a = 0; a < 6; a++) pm6[s][a] *= invd[(ab + a) >> 2];
    }

    float D0 = (0 == e && col == i) ? 1.f : 0.f;
    float D1 = (1 == e && col == i) ? 1.f : 0.f;
    float D2 = 0.f, D3 = 0.f;
    float acc = 0.f;

    // --- this half's edge list (groups with parity h) into registers ---
    const int g_all = gcnt[col];
    const int ch = (g_all - h + 1) >> 1;     // my group count
    int km = ch;
#pragma unroll
    for (int off = 32; off > 0; off >>= 1) {
        int o = __shfl_xor(km, off, 64);
        km = o > km ? o : km;
    }
    const int kmax = __builtin_amdgcn_readfirstlane(km);   // wave-uniform

    unsigned ep[GMR];
#pragma unroll
    for (int k = 0; k < GMR; k++) {
        unsigned pk = epk[(size_t)(2 * k + h) * NN + col];  // in-bounds; junk past g_all
        ep[k] = (2 * k + h < g_all) ? pk : ZPK;             // junk reads zero row (bcast)
    }

    const h2v S10 = {(_Float16)1.0f, (_Float16)0.0f};
    const h2v S01 = {(_Float16)0.0f, (_Float16)1.0f};
    char* const myrow0 = tmpb + col * ROWB + h * 12;

    for (int step = 0; step < steps; step++) {
        const int par = step & 1;
        char* const buf = tmpb + par * BUFB;

        // ---- phase A: accept(h0)/back(h1) + my 12B of the fp16 tmp row ----
        float r4 = D0 * pcb[0];
        r4 = fmaf(D1, pcb[1], r4); r4 = fmaf(D2, pcb[2], r4); r4 = fmaf(D3, pcb[3], r4);
        if (h == 0) acc += r4;
        float bj = h ? r4 : 0.f;

        float tv[6];
#pragma unroll
        for (int a = 0; a < 6; a++) {
            float x = D0 * pm6[0][a];
            x = fmaf(D1, pm6[1][a], x);
            x = fmaf(D2, pm6[2][a], x);
            x = fmaf(D3, pm6[3][a], x);
            tv[a] = x;
        }
        char* const myrow = myrow0 + par * BUFB;
        *(unsigned*)(myrow)     = ph2(tv[0], tv[1]);
        *(unsigned*)(myrow + 4) = ph2(tv[2], tv[3]);
        *(unsigned*)(myrow + 8) = ph2(tv[4], tv[5]);

#pragma unroll
        for (int off = 32; off > 0; off >>= 1) bj += __shfl_down(bj, off, 64);
        if (lane == 0) backp[par][wv] = bj;

        __syncthreads();   // the ONLY barrier per step

        // ---- phase B: gather, 2 groups per scalar branch (4 b64 in flight) ----
        float d0a = 0.f, d1a = 0.f, d2a = 0.f, d3a = 0.f;
        float d0b = 0.f, d1b = 0.f, d2b = 0.f, d3b = 0.f;
#pragma unroll
        for (int kc = 0; kc < GMR; kc += 2) {
            if (kc < kmax) {   // kmax in SGPR -> scalar branch, no VALU
                const unsigned pkA = ep[kc];
                const unsigned pkB = ep[kc + 1];
                const uint2 qA0 = *(const uint2*)(buf + (pkA & 0xffffu));
                const uint2 qA1 = *(const uint2*)(buf + (pkA >> 16));
                const uint2 qB0 = *(const uint2*)(buf + (pkB & 0xffffu));
                const uint2 qB1 = *(const uint2*)(buf + (pkB >> 16));
#ifdef HAVE_FDOT2
                d0a = __builtin_amdgcn_fdot2(bch2(qA0.x), S10, d0a, false);
                d1a = __builtin_amdgcn_fdot2(bch2(qA0.x), S01, d1a, false);
                d2a = __builtin_amdgcn_fdot2(bch2(qA0.y), S10, d2a, false);
                d3a = __builtin_amdgcn_fdot2(bch2(qA0.y), S01, d3a, false);
                d0a = __builtin_amdgcn_fdot2(bch2(qA1.x), S10, d0a, false);
                d1a = __builtin_amdgcn_fdot2(bch2(qA1.x), S01, d1a, false);
                d2a = __builtin_amdgcn_fdot2(bch2(qA1.y), S10, d2a, false);
                d3a = __builtin_amdgcn_fdot2(bch2(qA1.y), S01, d3a, false);
                d0b = __builtin_amdgcn_fdot2(bch2(qB0.x), S10, d0b, false);
                d1b = __builtin_amdgcn_fdot2(bch2(qB0.x), S01, d1b, false);
                d2b = __builtin_amdgcn_fdot2(bch2(qB0.y), S10, d2b, false);
                d3b = __builtin_amdgcn_fdot2(bch2(qB0.y), S01, d3b, false);
                d0b = __builtin_amdgcn_fdot2(bch2(qB1.x), S10, d0b, false);
                d1b = __builtin_amdgcn_fdot2(bch2(qB1.x), S01, d1b, false);
                d2b = __builtin_amdgcn_fdot2(bch2(qB1.y), S10, d2b, false);
                d3b = __builtin_amdgcn_fdot2(bch2(qB1.y), S01, d3b, false);
#else
                float2 f0 = h2f2(qA0.x), f1 = h2f2(qA0.y), f2 = h2f2(qA1.x), f3 = h2f2(qA1.y);
                d0a += f0.x + f2.x; d1a += f0.y + f2.y;
                d2a += f1.x + f3.x; d3a += f1.y + f3.y;
                float2 g0 = h2f2(qB0.x), g1 = h2f2(qB0.y), g2 = h2f2(qB1.x), g3 = h2f2(qB1.y);
                d0b += g0.x + g2.x; d1b += g0.y + g2.y;
                d2b += g1.x + g3.x; d3b += g1.y + g3.y;
#endif
            }
        }
        // rare tail beyond register capacity (per-lane guard vs junk entries)
        for (int k = GMR; k < kmax; k++) {
            unsigned pk = epk[(size_t)(2 * k + h) * NN + col];
            pk = (2 * k + h < g_all) ? pk : ZPK;
            const uint2 q0 = *(const uint2*)(buf + (pk & 0xffffu));
            const uint2 q1 = *(const uint2*)(buf + (pk >> 16));
            float2 f0 = h2f2(q0.x), f1 = h2f2(q0.y), f2 = h2f2(q1.x), f3 = h2f2(q1.y);
            d0a += f0.x + f2.x; d1a += f0.y + f2.y;
            d2a += f1.x + f3.x; d3a += f1.y + f3.y;
        }

        float d0 = d0a + d0b, d1 = d1a + d1b, d2 = d2a + d2b, d3 = d3a + d3b;

        // ---- combine the two halves of each col (same wave, lanes 2c/2c+1) ----
        d0 += __shfl_xor(d0, 1, 64);
        d1 += __shfl_xor(d1, 1, 64);
        d2 += __shfl_xor(d2, 1, 64);
        d3 += __shfl_xor(d3, 1, 64);

        // ---- restart (only the 2 col==i threads need `back`) ----
        if (col == i) {
            const float4 b0 = *(const float4*)(&backp[par][0]);
            const float4 b1 = *(const float4*)(&backp[par][4]);
            const float back = ((b0.x + b0.y) + (b0.z + b0.w)) +
                               ((b1.x + b1.y) + (b1.z + b1.w));
            if (e == 0) d0 = fmaf(back, 0.999f, d0);
            else        d1 = fmaf(back, 0.999f, d1);
        }
        D0 = d0; D1 = d1; D2 = d2; D3 = d3;
    }

    // final accept (h0 holds pacc and writes the output)
    float r4 = D0 * pcb[0];
    r4 = fmaf(D1, pcb[1], r4); r4 = fmaf(D2, pcb[2], r4); r4 = fmaf(D3, pcb[3], r4);
    if (h == 0) {
        acc += r4;
        out[((size_t)e * NN + i) * NN + col] = acc;
    }
}

// ---------------------------------------------------------------------------
extern "C" void kernel_launch(void* const* d_in, const int* in_sizes, int n_in,
                              void* d_out, int out_size, void* d_ws, size_t ws_size,
                              hipStream_t stream) {
    const float* vw  = (const float*)d_in[0];   // (N,N,V) fp32
    const float* adj = (const float*)d_in[1];   // (T,N,N) fp32 {0,1}
    const float* lrp = (const float*)d_in[2];   // (V,NTY,S,NAC) fp32
    const int* node_types = (const int*)d_in[3];
    const int* steps_p    = (const int*)d_in[4];

    float* ws       = (float*)d_ws;
    float* pol      = ws;                        // 1920 f
    float* inv_deg  = ws + 1920;                 // 768 f
    int*   gcnt     = (int*)(ws + 2688);         // 256 i
    unsigned* epk   = (unsigned*)(ws + 2944);    // CAPG*NN u32 = 48 KB
    int*   perm     = (int*)(ws + 2944 + CAPG * NN);  // 256 i

    k_setup<<<TT * NN + 64 + 1, 256, 0, stream>>>(adj, lrp, inv_deg, pol, epk, gcnt);
    k_sort<<<1, 256, 0, stream>>>(gcnt, perm);
    k_main<<<2 * NN, 512, 0, stream>>>(vw, node_types, pol, inv_deg, epk, gcnt,
                                       perm, steps_p, (float*)d_out);
}